// Round 1
// baseline (49.007 us; speedup 1.0000x reference)
//
#include <hip/hip_runtime.h>
#include <math.h>

// OrthogonalButterfly: X (1024 x 8192) fp32, 20 butterfly layers, stride 2^(l%10).
// Register-resident design: thread owns 32 rows of one column; 3 LDS ownership
// transposes (A: consecutive rows -> strides 1..16 local; B: rows mod 32 ->
// strides 32..512 local). Angle table precomputed (cos,sin) in d_ws, permuted
// so each thread reads 128B contiguous per layer.

#define NROW   1024
#define BATCH  8192
#define DEPTH  20
#define NANG   512
#define TAB_ELEMS (DEPTH * NANG)
#define TAB_BYTES ((size_t)TAB_ELEMS * 8)

// ---------------- angle table build ----------------
// table slot mapping per layer l (sp = l % 10):
//   A-layers (sp<=4, s=2^sp):  slot = a  (identity)
//   B-layers (sp>=5, sigma=2^(sp-5)): slot = g*16 + p, p = K*sigma + m,
//        a = K*32*sigma + 32*m + g
__global__ void build_tab_kernel(const float* __restrict__ ang,
                                 float2* __restrict__ tab) {
    int idx = blockIdx.x * blockDim.x + threadIdx.x;
    if (idx >= TAB_ELEMS) return;
    int l = idx >> 9;
    int slot = idx & (NANG - 1);
    int sp = l % 10;
    int a;
    if (sp <= 4) {
        a = slot;
    } else {
        int g = slot >> 4;
        int p = slot & 15;
        int sgp = sp - 5;                 // log2(sigma)
        int K = p >> sgp;
        int m = p & ((1 << sgp) - 1);
        a = (K << (5 + sgp)) | (m << 5) | g;
    }
    float th = ang[l * NANG + a];
    float sv, cv;
    sincosf(th, &sv, &cv);
    tab[idx] = make_float2(cv, sv);
}

// ---------------- main kernel ----------------
__device__ __forceinline__ void rot(float& a, float& b, float cv, float sv) {
    float x0 = a, x1 = b;
    a = cv * x0 + sv * x1;
    b = cv * x1 - sv * x0;
}

// One layer. S = stride (phase A) or sigma = stride/32 (phase B).
// y[i] holds: phase A -> row 32*sub + i ; phase B -> row sub + 32*i.
template<int S, bool PB, bool USE_TAB>
__device__ __forceinline__ void layer_one(float y[32],
                                          const float2* __restrict__ tabL,
                                          const float* __restrict__ angL,
                                          int sub) {
    float2 cs[16];
    if (USE_TAB) {
        const float4* t4 = reinterpret_cast<const float4*>(tabL + 16 * sub);
        #pragma unroll
        for (int u = 0; u < 8; ++u) {
            float4 q = t4[u];
            cs[2 * u]     = make_float2(q.x, q.y);
            cs[2 * u + 1] = make_float2(q.z, q.w);
        }
    } else {
        #pragma unroll
        for (int p = 0; p < 16; ++p) {
            int a;
            if (PB) {
                int K = p / S, m = p % S;          // S = sigma (compile-time)
                a = K * 32 * S + 32 * m + sub;
            } else {
                a = 16 * sub + p;
            }
            float th = angL[a];
            float sv, cv;
            __sincosf(th, &sv, &cv);
            cs[p] = make_float2(cv, sv);
        }
    }
    #pragma unroll
    for (int I = 0; I < 16 / S; ++I) {
        #pragma unroll
        for (int j = 0; j < S; ++j) {
            int i0 = I * 2 * S + j;
            int i1 = i0 + S;
            int p  = I * S + j;
            rot(y[i0], y[i1], cs[p].x, cs[p].y);
        }
    }
}

template<bool PB, bool USE_TAB>
__device__ __forceinline__ void group5(float y[32], const float2* tab,
                                       const float* ang, int lbase, int sub) {
    layer_one<1,  PB, USE_TAB>(y, tab + (lbase + 0) * NANG, ang + (lbase + 0) * NANG, sub);
    layer_one<2,  PB, USE_TAB>(y, tab + (lbase + 1) * NANG, ang + (lbase + 1) * NANG, sub);
    layer_one<4,  PB, USE_TAB>(y, tab + (lbase + 2) * NANG, ang + (lbase + 2) * NANG, sub);
    layer_one<8,  PB, USE_TAB>(y, tab + (lbase + 3) * NANG, ang + (lbase + 3) * NANG, sub);
    layer_one<16, PB, USE_TAB>(y, tab + (lbase + 4) * NANG, ang + (lbase + 4) * NANG, sub);
}

// LDS address for element (col c, row r):
//   c*1024 + (r XOR ((((r>>5) ^ c) & 7) << 2))
// Injects row-chunk and column into bank bits 2-4: b128 writes are
// octet-conflict-free, strided b32 reads are 2-way (free).
__device__ __forceinline__ void t_a2b(float y[32], float* lds, int c, int sub) {
    __syncthreads();
    {
        int xr = ((sub ^ c) & 7) << 2;
        float* base = lds + c * 1024 + 32 * sub;
        #pragma unroll
        for (int u = 0; u < 8; ++u) {
            *reinterpret_cast<float4*>(base + ((4 * u) ^ xr)) =
                make_float4(y[4 * u], y[4 * u + 1], y[4 * u + 2], y[4 * u + 3]);
        }
    }
    __syncthreads();
    #pragma unroll
    for (int k = 0; k < 32; ++k)
        y[k] = lds[c * 1024 + 32 * k + (sub ^ ((((k ^ c) & 7)) << 2))];
}

__device__ __forceinline__ void t_b2a(float y[32], float* lds, int c, int sub) {
    __syncthreads();
    #pragma unroll
    for (int k = 0; k < 32; ++k)
        lds[c * 1024 + 32 * k + (sub ^ ((((k ^ c) & 7)) << 2))] = y[k];
    __syncthreads();
    {
        int xr = ((sub ^ c) & 7) << 2;
        const float* base = lds + c * 1024 + 32 * sub;
        #pragma unroll
        for (int u = 0; u < 8; ++u) {
            float4 v = *reinterpret_cast<const float4*>(base + ((4 * u) ^ xr));
            y[4 * u]     = v.x;
            y[4 * u + 1] = v.y;
            y[4 * u + 2] = v.z;
            y[4 * u + 3] = v.w;
        }
    }
}

template<bool USE_TAB>
__global__ __launch_bounds__(512, 4) void butterfly_kernel(
        const float* __restrict__ X, const float* __restrict__ ang,
        const float2* __restrict__ tab, float* __restrict__ out) {
    __shared__ float lds[16 * 1024];    // 64 KB -> 2 blocks/CU
    int t = threadIdx.x;
    int c = t & 15;
    int sub = t >> 4;                   // [0,32)
    int bid = blockIdx.x;               // [0,512)
    // XCD-aware swizzle: 64 consecutive column-chunks per XCD (bijective).
    int L = ((bid & 7) << 6) | (bid >> 3);
    int col = (L << 4) + c;

    float y[32];
    const float* Xp = X + col;
    #pragma unroll
    for (int i = 0; i < 32; ++i)
        y[i] = Xp[(32 * sub + i) * BATCH];       // phase A: row = 32*sub + i

    group5<false, USE_TAB>(y, tab, ang, 0, sub);   // s = 1,2,4,8,16
    t_a2b(y, lds, c, sub);                         // -> phase B: row = sub + 32*k
    group5<true,  USE_TAB>(y, tab, ang, 5, sub);   // s = 32..512
    t_b2a(y, lds, c, sub);                         // -> phase A
    group5<false, USE_TAB>(y, tab, ang, 10, sub);  // s = 1..16
    t_a2b(y, lds, c, sub);                         // -> phase B
    group5<true,  USE_TAB>(y, tab, ang, 15, sub);  // s = 32..512

    float* Op = out + col;
    #pragma unroll
    for (int k = 0; k < 32; ++k)
        Op[(sub + 32 * k) * BATCH] = y[k];         // phase B layout store
}

extern "C" void kernel_launch(void* const* d_in, const int* in_sizes, int n_in,
                              void* d_out, int out_size, void* d_ws, size_t ws_size,
                              hipStream_t stream) {
    (void)in_sizes; (void)n_in; (void)out_size;
    const float* X   = (const float*)d_in[0];
    const float* ang = (const float*)d_in[1];
    float* out = (float*)d_out;

    bool use_tab = (d_ws != nullptr) && (ws_size >= TAB_BYTES);
    if (use_tab) {
        float2* tab = (float2*)d_ws;
        build_tab_kernel<<<(TAB_ELEMS + 255) / 256, 256, 0, stream>>>(ang, tab);
        butterfly_kernel<true><<<512, 512, 0, stream>>>(X, ang, tab, out);
    } else {
        butterfly_kernel<false><<<512, 512, 0, stream>>>(X, ang, nullptr, out);
    }
}